// Round 7
// baseline (20.807 us; speedup 1.0000x reference)
//
#include <hip/hip_runtime.h>
#include <math.h>

#define S_ 32
#define B_ 128
#define M_ 128
#define F_ 512
#define C_ 100
#define RWZ 136   // f16 row width (272 B rows, 16B-aligned) for Zf/BTg
#define RWE 120   // f16 row width (240 B rows, 16B-aligned) for EPT/ENT/Pt

typedef _Float16 f16;
typedef _Float16 f16x2 __attribute__((ext_vector_type(2)));
typedef _Float16 f16x4 __attribute__((ext_vector_type(4)));
typedef _Float16 f16x8 __attribute__((ext_vector_type(8)));
typedef float f32x4 __attribute__((ext_vector_type(4)));

// ws layout (bytes):
//   BTg  f16[112][RWZ]  @ 0       (30464 B, pad to 30720)
//   EPTg f16[128][RWE]  @ 30720   (30720 B)  exp(+2*beta), [m][c]
//   ENTg f16[128][RWE]  @ 61440   (30720 B)  exp(-2*beta), [m][c]
//   etag f32[128][128]  @ 92160   (65536 B)
#define WS_BT   0
#define WS_EPT  30720
#define WS_ENT  61440
#define WS_ETA  92160

// ---- k_pre: blocks 0..127 -> eta row b; blocks 128..131 -> f16 tables ----
__global__ __launch_bounds__(512) void k_pre(
    const float* __restrict__ x, const float* __restrict__ alpha0,
    const float* __restrict__ alpha, const float* __restrict__ beta,
    char* __restrict__ ws) {
  const int bid = blockIdx.x;
  const int tid = threadIdx.x;
  if (bid < B_) {
    float* etag = (float*)(ws + WS_ETA);
    const int lane = tid & 63, w = tid >> 6, l15 = lane & 15, lg = lane >> 4;
    const float4* x4 = (const float4*)x;
    const float4* a4 = (const float4*)alpha;
    float4 xr[8];
#pragma unroll
    for (int r = 0; r < 8; ++r) xr[r] = x4[bid * 128 + r * 16 + l15];
#pragma unroll
    for (int j = 0; j < 4; ++j) {
      int m = w * 16 + j * 4 + lg;
      float acc = 0.f;
#pragma unroll
      for (int r = 0; r < 8; ++r) {
        float4 av = a4[(size_t)m * 128 + r * 16 + l15];
        float4 xv = xr[r];
        acc = fmaf(av.x, xv.x, acc); acc = fmaf(av.y, xv.y, acc);
        acc = fmaf(av.z, xv.z, acc); acc = fmaf(av.w, xv.w, acc);
      }
      acc += __shfl_xor(acc, 1);
      acc += __shfl_xor(acc, 2);
      acc += __shfl_xor(acc, 4);
      acc += __shfl_xor(acc, 8);
      if (l15 == 0) {
        float l = alpha0[m] + acc;
        etag[bid * 128 + m] = 1.f / (1.f + __expf(-l));
      }
    }
  } else {
    f16* BTg = (f16*)(ws + WS_BT);
    f16* EPTg = (f16*)(ws + WS_EPT);
    f16* ENTg = (f16*)(ws + WS_ENT);
    const int base = (bid - B_) * 512;
    for (int i = base + tid; i < C_ * M_; i += 4 * 512) {
      int c = i >> 7, m = i & 127;
      float bv = beta[i];
      BTg[c * RWZ + m] = (f16)bv;
      EPTg[m * RWE + c] = (f16)__expf(2.f * bv);
      ENTg[m * RWE + c] = (f16)__expf(-2.f * bv);
    }
    // zero pad: BTg rows 100..111; EPT/ENT cols 100..119 (MFMA K-tail reads)
    for (int i = base + tid; i < 12 * RWZ; i += 4 * 512) BTg[100 * RWZ + i] = (f16)0.f;
    for (int i = base + tid; i < 128 * 32; i += 4 * 512) {
      int m = i >> 5, k = i & 31;
      if (k < 20) { EPTg[m * RWE + 100 + k] = (f16)0.f; ENTg[m * RWE + 100 + k] = (f16)0.f; }
    }
  }
}

// ---- k_main: grid (2 sh, 128 b), 512 threads = 8 waves; 16 s-rows/block ----
__global__ __launch_bounds__(512) void k_main(
    const float* __restrict__ Z, const int* __restrict__ y,
    const float* __restrict__ beta0, const char* __restrict__ ws,
    float* __restrict__ out) {
  const int sh = blockIdx.x;   // 0,1
  const int b = blockIdx.y;    // 0..127
  const int tid = threadIdx.x;
  const int lane = tid & 63;
  const int w = tid >> 6;      // wave 0..7
  const int l15 = lane & 15;
  const int lg = lane >> 4;    // 0..3

  const f16* BTg = (const f16*)(ws + WS_BT);
  const f16* EPTg = (const f16*)(ws + WS_EPT);
  const f16* ENTg = (const f16*)(ws + WS_ENT);
  const float* etag = (const float*)(ws + WS_ETA);

  __shared__ f16 Zf[16 * RWZ];       // 4352 B  [p][m]
  __shared__ float baseS[16 * 112];  // 7168 B
  __shared__ f16 Pt[16 * RWE];       // 3840 B  [p][c]
  __shared__ float PybS[16];

  const int yb = y[b];

  // ---- A: stage Z rows (16 s of this half) -> f16 LDS ----
  {
    int p = tid >> 5, q = tid & 31;
    float4 v = ((const float4*)Z)[((size_t)(sh * 16 + p) * B_ + b) * 32 + q];
    f16x4 h = {(f16)v.x, (f16)v.y, (f16)v.z, (f16)v.w};
    *(f16x4*)&Zf[p * RWZ + q * 4] = h;
  }
  __syncthreads();

  // ---- B: base[16 p][112 c] = Zf x BTg^T (K=m=128); B-frags from global ----
  if (w < 7) {
    const char* BTB = (const char*)BTg;
    const char* ZfB = (const char*)Zf;
    f16x8 bfr[4];
#pragma unroll
    for (int kc = 0; kc < 4; ++kc)
      bfr[kc] = *(const f16x8*)(BTB + (w * 16 + l15) * (RWZ * 2) + kc * 64 + lg * 16);
    f32x4 acc = {0.f, 0.f, 0.f, 0.f};
#pragma unroll
    for (int kc = 0; kc < 4; ++kc) {
      f16x8 a0 = *(const f16x8*)(ZfB + l15 * (RWZ * 2) + kc * 64 + lg * 16);
      acc = __builtin_amdgcn_mfma_f32_16x16x32_f16(a0, bfr[kc], acc, 0, 0, 0);
    }
    int col = w * 16 + l15;
    float b0v = (col < C_) ? beta0[col] : 0.f;
#pragma unroll
    for (int j = 0; j < 4; ++j) baseS[(lg * 4 + j) * 112 + col] = acc[j] + b0v;
  }
  __syncthreads();

  // ---- C: softmax rows; wave w -> p = 2w, 2w+1 ----
  {
#pragma unroll
    for (int k = 0; k < 2; ++k) {
      int p = w * 2 + k;
      float v1 = baseS[p * 112 + lane];
      float v2 = (lane < 36) ? baseS[p * 112 + 64 + lane] : -1e30f;
      float mx = fmaxf(v1, v2);
#pragma unroll
      for (int off = 32; off > 0; off >>= 1) mx = fmaxf(mx, __shfl_xor(mx, off));
      float e1 = __expf(v1 - mx);
      float e2 = (lane < 36) ? __expf(v2 - mx) : 0.f;
      float sm = e1 + e2;
#pragma unroll
      for (int off = 32; off > 0; off >>= 1) sm += __shfl_xor(sm, off);
      float rd = 1.f / sm;
      Pt[p * RWE + lane] = (f16)(e1 * rd);
      if (lane < 48) Pt[p * RWE + 64 + lane] = (f16)(lane < 36 ? e2 * rd : 0.f);
      if (lane == yb) PybS[p] = e1 * rd;
      if (lane + 64 == yb) PybS[p] = e2 * rd;
    }
  }
  __syncthreads();

  // ---- D: den± [16 p][128 m] = Pt x EPT/ENT^T (K=c=112) + epilogue ----
  {
    const char* PtB = (const char*)Pt;
    const char* EPB = (const char*)EPTg;
    const char* ENB = (const char*)ENTg;
    const int rowoff = (w * 16 + l15) * (RWE * 2);
    f16x8 bp[3], bn[3];
#pragma unroll
    for (int kc = 0; kc < 3; ++kc) {
      bp[kc] = *(const f16x8*)(EPB + rowoff + kc * 64 + lg * 16);
      bn[kc] = *(const f16x8*)(ENB + rowoff + kc * 64 + lg * 16);
    }
    f16x4 bp3 = *(const f16x4*)(EPB + rowoff + 192 + lg * 8);
    f16x4 bn3 = *(const f16x4*)(ENB + rowoff + 192 + lg * 8);
    f32x4 pA = {0.f, 0.f, 0.f, 0.f}, nA = {0.f, 0.f, 0.f, 0.f};
#pragma unroll
    for (int kc = 0; kc < 3; ++kc) {
      f16x8 a0 = *(const f16x8*)(PtB + l15 * (RWE * 2) + kc * 64 + lg * 16);
      pA = __builtin_amdgcn_mfma_f32_16x16x32_f16(a0, bp[kc], pA, 0, 0, 0);
      nA = __builtin_amdgcn_mfma_f32_16x16x32_f16(a0, bn[kc], nA, 0, 0, 0);
    }
    {
      f16x4 a3 = *(const f16x4*)(PtB + l15 * (RWE * 2) + 192 + lg * 8);
      pA = __builtin_amdgcn_mfma_f32_16x16x16f16(a3, bp3, pA, 0, 0, 0);
      nA = __builtin_amdgcn_mfma_f32_16x16x16f16(a3, bn3, nA, 0, 0, 0);
    }
    int m = w * 16 + l15;
    float epy = (float)EPTg[m * RWE + yb];
    float eny = (float)ENTg[m * RWE + yb];
    float eta_v = etag[b * M_ + m];
    float ome = 1.f - eta_v;
    float o = 0.f;
#pragma unroll
    for (int j = 0; j < 4; ++j) {
      int p = lg * 4 + j;
      float z = (float)Zf[p * RWZ + m];
      float pyb = PybS[p];
      o += (z > 0.f) ? fmaf(pyb, eta_v, (pyb * eny / nA[j]) * ome)
                     : fmaf(pyb * epy / pA[j], eta_v, pyb * ome);
    }
    o += __shfl_xor(o, 16);
    o += __shfl_xor(o, 32);
    if (lane < 16) atomicAdd(&out[b * M_ + w * 16 + lane], o);
  }
}

extern "C" void kernel_launch(void* const* d_in, const int* in_sizes, int n_in,
                              void* d_out, int out_size, void* d_ws, size_t ws_size,
                              hipStream_t stream) {
  const float* x = (const float*)d_in[0];
  const int* y = (const int*)d_in[1];
  const float* Z = (const float*)d_in[2];
  const float* alpha0 = (const float*)d_in[3];
  const float* alpha = (const float*)d_in[4];
  const float* beta0 = (const float*)d_in[5];
  const float* beta = (const float*)d_in[6];
  float* out = (float*)d_out;
  char* ws = (char*)d_ws;

  hipMemsetAsync(out, 0, (size_t)B_ * M_ * sizeof(float), stream);
  k_pre<<<dim3(B_ + 4), dim3(512), 0, stream>>>(x, alpha0, alpha, beta, ws);
  k_main<<<dim3(2, B_), dim3(512), 0, stream>>>(Z, y, beta0, ws, out);
}

// Round 8
// 19.253 us; speedup vs baseline: 1.0807x; 1.0807x over previous
//
#include <hip/hip_runtime.h>
#include <math.h>

#define S_ 32
#define B_ 128
#define M_ 128
#define F_ 512
#define C_ 100
#define RWZ 136   // f16 row stride for Zf (272 B)
#define RWP 136   // f16 row stride for Pt (272 B)

typedef _Float16 f16;
typedef _Float16 f16x4 __attribute__((ext_vector_type(4)));
typedef _Float16 f16x8 __attribute__((ext_vector_type(8)));
typedef float f32x4 __attribute__((ext_vector_type(4)));

// ws: MFMA-fragment-ordered tables (each chunk = 64 lanes x 16B = 1 KB bursts)
//  BTf @ 0     : 4 kc(m-chunks) x 7 rt(c-tiles) x 64 lane x 16B = 28672 B
//                chunk(kc,rt,lane) = beta[c=rt*16+(lane&15)][m0=kc*32+(lane>>4)*8 ..+8]
//  EPf @ 28672 : 4 kc(c-chunks) x 8 rt(m-tiles) x 64 x 16B = 32768 B  exp(+2*beta[c][m])
//  ENf @ 61440 : same, exp(-2*beta)   (c >= 100 slots are 0)
#define WS_BT 0
#define WS_EP 28672
#define WS_EN 61440

__global__ __launch_bounds__(512) void k_pre(const float* __restrict__ beta,
                                             char* __restrict__ ws) {
  __shared__ float betaS[C_ * M_];  // 51.2 KB
  const int tid = threadIdx.x;
  for (int i = tid; i < C_ * M_; i += 512) betaS[i] = beta[i];
  __syncthreads();
  const int ci = blockIdx.x * 512 + tid;  // 0..6143; active < 5888
  if (ci < 1792) {                        // BTf
    int lane = ci & 63, t = ci >> 6;
    int rt = t % 7, kc = t / 7;
    int c = rt * 16 + (lane & 15);
    int m0 = kc * 32 + (lane >> 4) * 8;
    f16x8 v;
#pragma unroll
    for (int i = 0; i < 8; ++i)
      v[i] = (c < C_) ? (f16)betaS[c * M_ + m0 + i] : (f16)0.f;
    *(f16x8*)(ws + WS_BT + (size_t)ci * 16) = v;
  } else if (ci < 3840) {                 // EPf
    int q = ci - 1792;
    int lane = q & 63, t = q >> 6;
    int m = (t & 7) * 16 + (lane & 15);
    int c0 = (t >> 3) * 32 + (lane >> 4) * 8;
    f16x8 v;
#pragma unroll
    for (int i = 0; i < 8; ++i) {
      int c = c0 + i;
      v[i] = (c < C_) ? (f16)__expf(2.f * betaS[c * M_ + m]) : (f16)0.f;
    }
    *(f16x8*)(ws + WS_EP + (size_t)q * 16) = v;
  } else if (ci < 5888) {                 // ENf
    int q = ci - 3840;
    int lane = q & 63, t = q >> 6;
    int m = (t & 7) * 16 + (lane & 15);
    int c0 = (t >> 3) * 32 + (lane >> 4) * 8;
    f16x8 v;
#pragma unroll
    for (int i = 0; i < 8; ++i) {
      int c = c0 + i;
      v[i] = (c < C_) ? (f16)__expf(-2.f * betaS[c * M_ + m]) : (f16)0.f;
    }
    *(f16x8*)(ws + WS_EN + (size_t)q * 16) = v;
  }
}

// One block per b; 512 threads = 8 waves; direct out write (no atomics).
__global__ __launch_bounds__(512) void k_main(
    const float* __restrict__ x, const int* __restrict__ y,
    const float* __restrict__ Z, const float* __restrict__ alpha0,
    const float* __restrict__ alpha, const float* __restrict__ beta0,
    const float* __restrict__ beta, const char* __restrict__ ws,
    float* __restrict__ out) {
  const int b = blockIdx.x;
  const int tid = threadIdx.x;
  const int lane = tid & 63;
  const int w = tid >> 6;    // wave 0..7
  const int l15 = lane & 15;
  const int lg = lane >> 4;  // 0..3

  __shared__ f16 Zf[S_ * RWZ];       // 8704 B  [p][m]
  __shared__ float baseS[S_ * 112];  // 14336 B
  __shared__ f16 Pt[S_ * RWP];       // 8704 B  [p][c], c 100..127 zeroed
  __shared__ float PybS[S_];
  __shared__ float etaS[M_];

  const int yb = y[b];

  // ---- A: stage Z -> f16 LDS, plus eta wave-GEMV ----
  {
    const float4* Z4 = (const float4*)Z;
#pragma unroll
    for (int k = 0; k < 2; ++k) {
      int i4 = tid + k * 512;  // 0..1023
      int p = i4 >> 5, q = i4 & 31;
      float4 v = Z4[((size_t)p * B_ + b) * 32 + q];
      f16x4 h = {(f16)v.x, (f16)v.y, (f16)v.z, (f16)v.w};
      *(f16x4*)&Zf[p * RWZ + q * 4] = h;
    }
    const float4* x4 = (const float4*)x;
    const float4* a4 = (const float4*)alpha;
    float4 xr[8];
#pragma unroll
    for (int r = 0; r < 8; ++r) xr[r] = x4[b * 128 + r * 16 + l15];
#pragma unroll
    for (int j = 0; j < 4; ++j) {
      int m = w * 16 + j * 4 + lg;
      float acc = 0.f;
#pragma unroll
      for (int r = 0; r < 8; ++r) {
        float4 av = a4[(size_t)m * 128 + r * 16 + l15];
        float4 xv = xr[r];
        acc = fmaf(av.x, xv.x, acc); acc = fmaf(av.y, xv.y, acc);
        acc = fmaf(av.z, xv.z, acc); acc = fmaf(av.w, xv.w, acc);
      }
      acc += __shfl_xor(acc, 1);
      acc += __shfl_xor(acc, 2);
      acc += __shfl_xor(acc, 4);
      acc += __shfl_xor(acc, 8);
      if (l15 == 0) {
        float l = alpha0[m] + acc;
        etaS[m] = 1.f / (1.f + __expf(-l));
      }
    }
  }
  __syncthreads();

  // ---- B: base[32 p][112 c] = Zf x beta^T (K=m=128); frags coalesced ----
  if (w < 7) {
    f16x8 bfr[4];
#pragma unroll
    for (int kc = 0; kc < 4; ++kc)
      bfr[kc] = *(const f16x8*)(ws + WS_BT + (size_t)((kc * 7 + w) * 64 + lane) * 16);
    f32x4 acc0 = {0.f, 0.f, 0.f, 0.f}, acc1 = {0.f, 0.f, 0.f, 0.f};
    const char* ZfB = (const char*)Zf;
#pragma unroll
    for (int kc = 0; kc < 4; ++kc) {
      f16x8 a0 = *(const f16x8*)(ZfB + l15 * (RWZ * 2) + kc * 64 + lg * 16);
      f16x8 a1 = *(const f16x8*)(ZfB + (16 + l15) * (RWZ * 2) + kc * 64 + lg * 16);
      acc0 = __builtin_amdgcn_mfma_f32_16x16x32_f16(a0, bfr[kc], acc0, 0, 0, 0);
      acc1 = __builtin_amdgcn_mfma_f32_16x16x32_f16(a1, bfr[kc], acc1, 0, 0, 0);
    }
    int col = w * 16 + l15;
    float b0v = (col < C_) ? beta0[col] : 0.f;
#pragma unroll
    for (int j = 0; j < 4; ++j) {
      baseS[(lg * 4 + j) * 112 + col] = acc0[j] + b0v;
      baseS[(16 + lg * 4 + j) * 112 + col] = acc1[j] + b0v;
    }
  }
  __syncthreads();

  // ---- C: softmax; wave w -> rows p = 4w..4w+3; Pt zero-padded to c=128 ----
  {
#pragma unroll
    for (int k = 0; k < 4; ++k) {
      int p = w * 4 + k;
      float v1 = baseS[p * 112 + lane];
      float v2 = (lane < 36) ? baseS[p * 112 + 64 + lane] : -1e30f;
      float mx = fmaxf(v1, v2);
#pragma unroll
      for (int off = 32; off > 0; off >>= 1) mx = fmaxf(mx, __shfl_xor(mx, off));
      float e1 = __expf(v1 - mx);
      float e2 = (lane < 36) ? __expf(v2 - mx) : 0.f;
      float sm = e1 + e2;
#pragma unroll
      for (int off = 32; off > 0; off >>= 1) sm += __shfl_xor(sm, off);
      float rd = 1.f / sm;
      Pt[p * RWP + lane] = (f16)(e1 * rd);
      Pt[p * RWP + 64 + lane] = (f16)((lane < 36) ? e2 * rd : 0.f);
      if (lane == yb) PybS[p] = e1 * rd;
      if (lane + 64 == yb) PybS[p] = e2 * rd;
    }
  }
  __syncthreads();

  // ---- D: den± [32 p][128 m] = Pt x exp-tables^T (K=c=128) + epilogue ----
  {
    f16x8 bp[4], bn[4];
#pragma unroll
    for (int kc = 0; kc < 4; ++kc) {
      bp[kc] = *(const f16x8*)(ws + WS_EP + (size_t)((kc * 8 + w) * 64 + lane) * 16);
      bn[kc] = *(const f16x8*)(ws + WS_EN + (size_t)((kc * 8 + w) * 64 + lane) * 16);
    }
    f32x4 pA0 = {0.f,0.f,0.f,0.f}, pA1 = {0.f,0.f,0.f,0.f};
    f32x4 nA0 = {0.f,0.f,0.f,0.f}, nA1 = {0.f,0.f,0.f,0.f};
    const char* PtB = (const char*)Pt;
#pragma unroll
    for (int kc = 0; kc < 4; ++kc) {
      f16x8 a0 = *(const f16x8*)(PtB + l15 * (RWP * 2) + kc * 64 + lg * 16);
      f16x8 a1 = *(const f16x8*)(PtB + (16 + l15) * (RWP * 2) + kc * 64 + lg * 16);
      pA0 = __builtin_amdgcn_mfma_f32_16x16x32_f16(a0, bp[kc], pA0, 0, 0, 0);
      nA0 = __builtin_amdgcn_mfma_f32_16x16x32_f16(a0, bn[kc], nA0, 0, 0, 0);
      pA1 = __builtin_amdgcn_mfma_f32_16x16x32_f16(a1, bp[kc], pA1, 0, 0, 0);
      nA1 = __builtin_amdgcn_mfma_f32_16x16x32_f16(a1, bn[kc], nA1, 0, 0, 0);
    }
    int m = w * 16 + l15;
    float bym = beta[yb * M_ + m];
    float epy = __expf(2.f * bym), eny = __expf(-2.f * bym);
    float eta_v = etaS[m];
    float ome = 1.f - eta_v;
    float o = 0.f;
#pragma unroll
    for (int j = 0; j < 4; ++j) {
      {
        int p = lg * 4 + j;
        float z = (float)Zf[p * RWZ + m];
        float pyb = PybS[p];
        o += (z > 0.f) ? fmaf(pyb, eta_v, (pyb * eny / nA0[j]) * ome)
                       : fmaf(pyb * epy / pA0[j], eta_v, pyb * ome);
      }
      {
        int p = 16 + lg * 4 + j;
        float z = (float)Zf[p * RWZ + m];
        float pyb = PybS[p];
        o += (z > 0.f) ? fmaf(pyb, eta_v, (pyb * eny / nA1[j]) * ome)
                       : fmaf(pyb * epy / pA1[j], eta_v, pyb * ome);
      }
    }
    o += __shfl_xor(o, 16);
    o += __shfl_xor(o, 32);
    if (lane < 16) out[b * M_ + w * 16 + l15] = o;
  }
}

extern "C" void kernel_launch(void* const* d_in, const int* in_sizes, int n_in,
                              void* d_out, int out_size, void* d_ws, size_t ws_size,
                              hipStream_t stream) {
  const float* x = (const float*)d_in[0];
  const int* y = (const int*)d_in[1];
  const float* Z = (const float*)d_in[2];
  const float* alpha0 = (const float*)d_in[3];
  const float* alpha = (const float*)d_in[4];
  const float* beta0 = (const float*)d_in[5];
  const float* beta = (const float*)d_in[6];
  float* out = (float*)d_out;
  char* ws = (char*)d_ws;

  k_pre<<<dim3(12), dim3(512), 0, stream>>>(beta, ws);
  k_main<<<dim3(B_), dim3(512), 0, stream>>>(x, y, Z, alpha0, alpha, beta0,
                                             beta, ws, out);
}

// Round 9
// 14.671 us; speedup vs baseline: 1.4182x; 1.3123x over previous
//
#include <hip/hip_runtime.h>
#include <math.h>

#define S_ 32
#define B_ 128
#define M_ 128
#define F_ 512
#define C_ 100
#define SB 16     // s-rows per k_main block
#define RWZ 136   // f16 row stride for Zf (272 B)
#define RWP 136   // f16 row stride for Pt (272 B)

typedef _Float16 f16;
typedef _Float16 f16x4 __attribute__((ext_vector_type(4)));
typedef _Float16 f16x8 __attribute__((ext_vector_type(8)));
typedef float f32x4 __attribute__((ext_vector_type(4)));

// ws layout (bytes):
//  BTf  @ 0     : 4 kc x 7 ct x 64 lane x 16B = 28672   beta frags   [B-op of phase B]
//  EPf  @ 28672 : 4 kc x 8 mt x 64 lane x 16B = 32768   exp(+2*beta) [B-op of phase D]
//  ENf  @ 61440 : 32768                                 exp(-2*beta)
//  etag @ 94208 : f32[128][128] = 65536
#define WS_BT  0
#define WS_EP  28672
#define WS_EN  61440
#define WS_ETA 94208

// ---- k_pre: blocks 0..127 -> eta row + zero out row; 128..139 -> tables ----
__global__ __launch_bounds__(512) void k_pre(
    const float* __restrict__ x, const float* __restrict__ alpha0,
    const float* __restrict__ alpha, const float* __restrict__ beta,
    char* __restrict__ ws, float* __restrict__ out) {
  const int bid = blockIdx.x;
  const int tid = threadIdx.x;
  __shared__ float betaS[C_ * M_];  // used by table blocks only
  if (bid < B_) {
    float* etag = (float*)(ws + WS_ETA);
    const int lane = tid & 63, w = tid >> 6, l15 = lane & 15, lg = lane >> 4;
    if (tid < M_) out[bid * M_ + tid] = 0.f;
    const float4* x4 = (const float4*)x;
    const float4* a4 = (const float4*)alpha;
    float4 xr[8];
#pragma unroll
    for (int r = 0; r < 8; ++r) xr[r] = x4[bid * 128 + r * 16 + l15];
#pragma unroll
    for (int j = 0; j < 4; ++j) {
      int m = w * 16 + j * 4 + lg;
      float acc = 0.f;
#pragma unroll
      for (int r = 0; r < 8; ++r) {
        float4 av = a4[(size_t)m * 128 + r * 16 + l15];
        float4 xv = xr[r];
        acc = fmaf(av.x, xv.x, acc); acc = fmaf(av.y, xv.y, acc);
        acc = fmaf(av.z, xv.z, acc); acc = fmaf(av.w, xv.w, acc);
      }
      acc += __shfl_xor(acc, 1);
      acc += __shfl_xor(acc, 2);
      acc += __shfl_xor(acc, 4);
      acc += __shfl_xor(acc, 8);
      if (l15 == 0) {
        float l = alpha0[m] + acc;
        etag[bid * 128 + m] = 1.f / (1.f + __expf(-l));
      }
    }
  } else {
    for (int i = tid; i < C_ * M_; i += 512) betaS[i] = beta[i];
    __syncthreads();
    const int ci = (bid - B_) * 512 + tid;  // 0..6143; active < 5888
    if (ci < 1792) {                        // BTf: frag(kc,ct): beta[c][m-seg]
      int lane = ci & 63, t = ci >> 6;
      int ct = t % 7, kc = t / 7;
      int c = ct * 16 + (lane & 15);
      int m0 = kc * 32 + (lane >> 4) * 8;
      f16x8 v;
#pragma unroll
      for (int i = 0; i < 8; ++i)
        v[i] = (c < C_) ? (f16)betaS[c * M_ + m0 + i] : (f16)0.f;
      *(f16x8*)(ws + WS_BT + (size_t)ci * 16) = v;
    } else if (ci < 3840) {                 // EPf: frag(kc,mt): exp(+2*beta[c-seg][m])
      int q = ci - 1792;
      int lane = q & 63, t = q >> 6;
      int m = (t & 7) * 16 + (lane & 15);
      int c0 = (t >> 3) * 32 + (lane >> 4) * 8;
      f16x8 v;
#pragma unroll
      for (int i = 0; i < 8; ++i) {
        int c = c0 + i;
        v[i] = (c < C_) ? (f16)__expf(2.f * betaS[c * M_ + m]) : (f16)0.f;
      }
      *(f16x8*)(ws + WS_EP + (size_t)q * 16) = v;
    } else if (ci < 5888) {                 // ENf
      int q = ci - 3840;
      int lane = q & 63, t = q >> 6;
      int m = (t & 7) * 16 + (lane & 15);
      int c0 = (t >> 3) * 32 + (lane >> 4) * 8;
      f16x8 v;
#pragma unroll
      for (int i = 0; i < 8; ++i) {
        int c = c0 + i;
        v[i] = (c < C_) ? (f16)__expf(-2.f * betaS[c * M_ + m]) : (f16)0.f;
      }
      *(f16x8*)(ws + WS_EN + (size_t)q * 16) = v;
    }
  }
}

// ---- k_main: grid (2 sh, 128 b), 512 thr = 8 waves; 16 s-rows per block ----
__global__ __launch_bounds__(512) void k_main(
    const int* __restrict__ y, const float* __restrict__ Z,
    const float* __restrict__ beta0, const float* __restrict__ beta,
    const char* __restrict__ ws, float* __restrict__ out) {
  const int sh = blockIdx.x;   // 0,1
  const int b = blockIdx.y;    // 0..127
  const int tid = threadIdx.x;
  const int lane = tid & 63;
  const int w = tid >> 6;      // 0..7
  const int l15 = lane & 15;
  const int lg = lane >> 4;    // 0..3

  __shared__ f16 Zf[SB * RWZ];       // 4352 B [p][m]
  __shared__ float baseS[SB * 112];  // 7168 B
  __shared__ f16 Pt[SB * RWP];       // 4352 B [p][c], c>=100 zeroed
  __shared__ float PybS[SB];

  const int yb = y[b];
  const int m = w * 16 + l15;

  // ---- A: stage 16 Z rows -> f16 LDS (one float4 per thread) ----
  {
    int p = tid >> 5, q = tid & 31;
    float4 v = ((const float4*)Z)[((size_t)(sh * SB + p) * B_ + b) * 32 + q];
    f16x4 h = {(f16)v.x, (f16)v.y, (f16)v.z, (f16)v.w};
    *(f16x4*)&Zf[p * RWZ + q * 4] = h;
  }

  // Issue-early: phase-D fragments + epilogue scalars (hide under B+C)
  f16x8 bp[4], bn[4];
#pragma unroll
  for (int kc = 0; kc < 4; ++kc) {
    bp[kc] = *(const f16x8*)(ws + WS_EP + (size_t)((kc * 8 + w) * 64 + lane) * 16);
    bn[kc] = *(const f16x8*)(ws + WS_EN + (size_t)((kc * 8 + w) * 64 + lane) * 16);
  }
  const float bym = beta[yb * M_ + m];
  const float eta_v = ((const float*)(ws + WS_ETA))[b * M_ + m];
  // Phase-B fragments
  f16x8 bfr[4];
#pragma unroll
  for (int kc = 0; kc < 4; ++kc)
    bfr[kc] = *(const f16x8*)(ws + WS_BT + (size_t)((kc * 7 + (w % 7)) * 64 + lane) * 16);

  __syncthreads();

  // ---- B: base[16 p][112 c] = Zf x beta^T (K=128) ----
  if (w < 7) {
    f32x4 acc = {0.f, 0.f, 0.f, 0.f};
    const char* ZfB = (const char*)Zf;
#pragma unroll
    for (int kc = 0; kc < 4; ++kc) {
      f16x8 a0 = *(const f16x8*)(ZfB + l15 * (RWZ * 2) + kc * 64 + lg * 16);
      acc = __builtin_amdgcn_mfma_f32_16x16x32_f16(a0, bfr[kc], acc, 0, 0, 0);
    }
    int col = w * 16 + l15;
    float b0v = (col < C_) ? beta0[col] : 0.f;
#pragma unroll
    for (int j = 0; j < 4; ++j) baseS[(lg * 4 + j) * 112 + col] = acc[j] + b0v;
  }
  __syncthreads();

  // ---- C: softmax; wave w -> rows p = 2w, 2w+1 ----
  {
#pragma unroll
    for (int k = 0; k < 2; ++k) {
      int p = w * 2 + k;
      float v1 = baseS[p * 112 + lane];
      float v2 = (lane < 36) ? baseS[p * 112 + 64 + lane] : -1e30f;
      float mx = fmaxf(v1, v2);
#pragma unroll
      for (int off = 32; off > 0; off >>= 1) mx = fmaxf(mx, __shfl_xor(mx, off));
      float e1 = __expf(v1 - mx);
      float e2 = (lane < 36) ? __expf(v2 - mx) : 0.f;
      float sm = e1 + e2;
#pragma unroll
      for (int off = 32; off > 0; off >>= 1) sm += __shfl_xor(sm, off);
      float rd = 1.f / sm;
      Pt[p * RWP + lane] = (f16)(e1 * rd);
      Pt[p * RWP + 64 + lane] = (f16)((lane < 36) ? e2 * rd : 0.f);
      if (lane == yb) PybS[p] = e1 * rd;
      if (lane + 64 == yb) PybS[p] = e2 * rd;
    }
  }
  __syncthreads();

  // ---- D: den± [16 p][128 m] = Pt x exp-tables^T (K=128) + epilogue ----
  {
    f32x4 pA = {0.f, 0.f, 0.f, 0.f}, nA = {0.f, 0.f, 0.f, 0.f};
    const char* PtB = (const char*)Pt;
#pragma unroll
    for (int kc = 0; kc < 4; ++kc) {
      f16x8 a0 = *(const f16x8*)(PtB + l15 * (RWP * 2) + kc * 64 + lg * 16);
      pA = __builtin_amdgcn_mfma_f32_16x16x32_f16(a0, bp[kc], pA, 0, 0, 0);
      nA = __builtin_amdgcn_mfma_f32_16x16x32_f16(a0, bn[kc], nA, 0, 0, 0);
    }
    float epy = __expf(2.f * bym), eny = __expf(-2.f * bym);
    float ome = 1.f - eta_v;
    float o = 0.f;
#pragma unroll
    for (int j = 0; j < 4; ++j) {
      int p = lg * 4 + j;
      float z = (float)Zf[p * RWZ + m];
      float pyb = PybS[p];
      o += (z > 0.f) ? fmaf(pyb, eta_v, (pyb * eny / nA[j]) * ome)
                     : fmaf(pyb * epy / pA[j], eta_v, pyb * ome);
    }
    o += __shfl_xor(o, 16);
    o += __shfl_xor(o, 32);
    if (lane < 16) atomicAdd(&out[b * M_ + w * 16 + l15], o);
  }
}

extern "C" void kernel_launch(void* const* d_in, const int* in_sizes, int n_in,
                              void* d_out, int out_size, void* d_ws, size_t ws_size,
                              hipStream_t stream) {
  const float* x = (const float*)d_in[0];
  const int* y = (const int*)d_in[1];
  const float* Z = (const float*)d_in[2];
  const float* alpha0 = (const float*)d_in[3];
  const float* alpha = (const float*)d_in[4];
  const float* beta0 = (const float*)d_in[5];
  const float* beta = (const float*)d_in[6];
  float* out = (float*)d_out;
  char* ws = (char*)d_ws;

  k_pre<<<dim3(B_ + 12), dim3(512), 0, stream>>>(x, alpha0, alpha, beta, ws, out);
  k_main<<<dim3(2, B_), dim3(512), 0, stream>>>(y, Z, beta0, beta, ws, out);
}